// Round 2
// 422.749 us; speedup vs baseline: 1.0737x; 1.0737x over previous
//
#include <hip/hip_runtime.h>
#include <math.h>

#define EPS 1e-5f
#define NROWS 1000000
#define C 64
#define B 8
#define CTX 256

typedef __attribute__((ext_vector_type(4))) float f32x4;

// ---------------------------------------------------------------------------
// Kernel 1: h = silu(dataset_token) @ W^T + b
//   One WAVE per output element (8*128 = 1024 waves; 256 blocks x 256 thr).
//   Lane l reads W[k*256 + l*4 .. +3] (coalesced float4: 64 lanes cover the
//   full 1 KB row in ONE wave-load) and the matching dt float4, silu's it
//   in-register, then 6-step shuffle reduction. Replaces the old 1-block
//   version whose lane-strided (1 KB apart) W reads serialized ~262K cache
//   line transactions through a single CU's L1.
//   ws[0   ..511] = shift   (h[:, :64],  layout [j*64 + c])
//   ws[512..1023] = 1+scale (h[:, 64:],  layout [j*64 + c])
// ---------------------------------------------------------------------------
__global__ __launch_bounds__(256) void token_gemm(
        const float* __restrict__ dt, const float* __restrict__ W,
        const float* __restrict__ bias, float* __restrict__ ws) {
    int wave = (blockIdx.x << 2) + (threadIdx.x >> 6);  // 0..1023
    int lane = threadIdx.x & 63;
    int j = wave >> 7;                                  // 0..7   batch row
    int k = wave & 127;                                 // 0..127 output feature

    f32x4 wv = ((const f32x4*)(W  + k * CTX))[lane];    // coalesced 1KB/wave
    f32x4 dv = ((const f32x4*)(dt + j * CTX))[lane];    // broadcast-ish, L2

    // silu in-register
    f32x4 s;
    s.x = dv.x / (1.0f + expf(-dv.x));
    s.y = dv.y / (1.0f + expf(-dv.y));
    s.z = dv.z / (1.0f + expf(-dv.z));
    s.w = dv.w / (1.0f + expf(-dv.w));

    float acc = wv.x * s.x + wv.y * s.y + wv.z * s.z + wv.w * s.w;
    #pragma unroll
    for (int m = 32; m >= 1; m >>= 1) acc += __shfl_xor(acc, m, 64);

    if (lane == 0) {
        acc += bias[k];
        if (k < C) ws[j * C + k] = acc;                     // shift
        else       ws[512 + j * C + (k - C)] = 1.0f + acc;  // 1 + scale
    }
}

// ---------------------------------------------------------------------------
// Kernel 2: per-row LayerNorm + FiLM modulation.
//   16 lanes per row, one float4 per lane (C=64). 256 threads -> 16 rows/block.
//   h (4 KB) read directly through L1/L2 (hot) -- no LDS stage, no barrier.
//   Non-temporal hints on the 512 MB streaming x/out traffic.
// ---------------------------------------------------------------------------
__global__ __launch_bounds__(256) void ln_mod(
        const float* __restrict__ x, const float* __restrict__ gamma,
        const float* __restrict__ beta, const int* __restrict__ coors,
        const float* __restrict__ h, float* __restrict__ out, int n) {
    int t = threadIdx.x;
    int group = t >> 4;                     // 0..15 (row within block)
    int lane  = t & 15;                     // 0..15 (float4 within row)
    int row = blockIdx.x * 16 + group;
    if (row >= n) return;

    f32x4 v = __builtin_nontemporal_load((const f32x4*)x + row * 16 + lane);

    float s  = v.x + v.y + v.z + v.w;
    float ss = v.x * v.x + v.y * v.y + v.z * v.z + v.w * v.w;
    #pragma unroll
    for (int m = 1; m < 16; m <<= 1) {
        s  += __shfl_xor(s,  m, 16);
        ss += __shfl_xor(ss, m, 16);
    }
    float mu   = s * (1.0f / 64.0f);
    float var  = ss * (1.0f / 64.0f) - mu * mu;
    float rstd = rsqrtf(var + EPS);

    int bidx = __ldg(coors + row * 4);      // batch index (col 0 of coors)

    f32x4 g  = ((const f32x4*)gamma)[lane];                 // L1-hot
    f32x4 be = ((const f32x4*)beta)[lane];                  // L1-hot
    f32x4 sc = ((const f32x4*)(h + 512 + bidx * C))[lane];  // 1+scale, L1-hot
    f32x4 sf = ((const f32x4*)(h + bidx * C))[lane];        // shift,   L1-hot

    f32x4 o;
    o.x = ((v.x - mu) * rstd * g.x + be.x) * sc.x + sf.x;
    o.y = ((v.y - mu) * rstd * g.y + be.y) * sc.y + sf.y;
    o.z = ((v.z - mu) * rstd * g.z + be.z) * sc.z + sf.z;
    o.w = ((v.w - mu) * rstd * g.w + be.w) * sc.w + sf.w;

    __builtin_nontemporal_store(o, (f32x4*)out + row * 16 + lane);
}

extern "C" void kernel_launch(void* const* d_in, const int* in_sizes, int n_in,
                              void* d_out, int out_size, void* d_ws, size_t ws_size,
                              hipStream_t stream) {
    const float* x     = (const float*)d_in[0];  // (N, 64)
    const float* dt    = (const float*)d_in[1];  // (8, 256)
    const float* gamma = (const float*)d_in[2];  // (64,)
    const float* beta  = (const float*)d_in[3];  // (64,)
    const float* W     = (const float*)d_in[4];  // (128, 256)
    const float* bias  = (const float*)d_in[5];  // (128,)
    const int*   coors = (const int*)d_in[6];    // (N, 4) int32
    float* out = (float*)d_out;
    float* ws  = (float*)d_ws;                   // 1024 floats used

    token_gemm<<<256, 256, 0, stream>>>(dt, W, bias, ws);

    int nblocks = (NROWS + 15) / 16;             // 62500
    ln_mod<<<nblocks, 256, 0, stream>>>(x, gamma, beta, coors, ws, out, NROWS);
}